// Round 1
// baseline (2725.633 us; speedup 1.0000x reference)
//
#include <hip/hip_runtime.h>

#define HDIM 256
#define MDIM 64
#define GNUM 128
#define KT 16

// ---------------- edge scatter: neigh_sum[src] += x[dst], deg[src] += 1 ----------------
__global__ __launch_bounds__(256) void edge_scatter_k(
    const float* __restrict__ x, const int* __restrict__ ei,
    float* __restrict__ neigh, float* __restrict__ deg, int E) {
  int wave = blockIdx.x * 4 + (threadIdx.x >> 6);
  int lane = threadIdx.x & 63;
  if (wave >= E) return;
  int src = ei[wave];
  int dst = ei[E + wave];
  const float4* xr = reinterpret_cast<const float4*>(x + (size_t)dst * HDIM);
  float* nr = neigh + (size_t)src * HDIM;
  float4 v = xr[lane];
  unsafeAtomicAdd(&nr[lane * 4 + 0], v.x);
  unsafeAtomicAdd(&nr[lane * 4 + 1], v.y);
  unsafeAtomicAdd(&nr[lane * 4 + 2], v.z);
  unsafeAtomicAdd(&nr[lane * 4 + 3], v.w);
  if (lane == 0) unsafeAtomicAdd(&deg[src], 1.0f);
}

// ---------------- per-node scale = deg>0 ? 1/deg : 0 ; per-graph node counts ----------------
__global__ __launch_bounds__(256) void finalize_k(
    const float* __restrict__ deg, float* __restrict__ scale,
    const int* __restrict__ batch, float* __restrict__ counts, int N) {
  int i = blockIdx.x * 256 + threadIdx.x;
  if (i >= N) return;
  float d = deg[i];
  scale[i] = d > 0.0f ? 1.0f / d : 0.0f;
  unsafeAtomicAdd(&counts[batch[i]], 1.0f);
}

// ---------------- fused: feat=concat(x,agg,x*agg); h=relu(feat@W1+b1); emb=h@W2+b2;
//                  sums[batch[n]] += emb ----------------
// Block: 256 threads, 64 nodes. GEMM1 thread (cx,ny): nodes 4ny..4ny+3, cols {4cx+64j+jj}.
__global__ __launch_bounds__(256, 2) void fused_mlp_pool_k(
    const float* __restrict__ x, const float* __restrict__ neigh,
    const float* __restrict__ scale, const int* __restrict__ batch,
    const float* __restrict__ W1, const float* __restrict__ b1,
    const float* __restrict__ W2, const float* __restrict__ b2,
    float* __restrict__ sums, int N) {
  __shared__ float Bs[KT][HDIM];   // 16 KB   W1 k-tile
  __shared__ float As[KT][68];     // 4.25 KB feat k-tile (pad 68: conflict-free, 16B-aligned)
  __shared__ float Hs[64][68];     // 17 KB   h chunk for GEMM2

  const int t  = threadIdx.x;
  const int cx = t & 15;
  const int ny = t >> 4;
  const int n0 = blockIdx.x * 64;

  float acc[4][16];                // [node i][col 4j+jj]
  #pragma unroll
  for (int i = 0; i < 4; ++i)
    #pragma unroll
    for (int j = 0; j < 16; ++j) acc[i][j] = 0.0f;

  for (int kt = 0; kt < 48; ++kt) {
    const int seg = kt >> 4;             // 0:x  1:agg  2:x*agg
    const int kk  = (kt & 15) * KT;      // col base within segment
    // ---- stage A (feat tile, computed on the fly), As[c][n] ----
    #pragma unroll
    for (int r = 0; r < 4; ++r) {
      int n = ny + 16 * r;               // reuse (cx,ny) as (c,nload-part)
      int node = n0 + n;
      float v = 0.0f;
      if (node < N) {
        size_t base = (size_t)node * HDIM + kk + cx;
        if (seg == 0) {
          v = x[base];
        } else {
          float a = neigh[base] * scale[node];
          v = (seg == 1) ? a : x[base] * a;
        }
      }
      As[cx][n] = v;
    }
    // ---- stage B (16 rows of W1) as float4 ----
    {
      const float4* W1v = reinterpret_cast<const float4*>(W1 + (size_t)kt * KT * HDIM);
      float4* Bsv = reinterpret_cast<float4*>(&Bs[0][0]);
      #pragma unroll
      for (int i = 0; i < 4; ++i) {
        int f = t + 256 * i;
        Bsv[f] = W1v[f];
      }
    }
    __syncthreads();
    // ---- inner product: 64 FMA / k / thread ----
    #pragma unroll
    for (int k = 0; k < KT; ++k) {
      float4 a4 = *reinterpret_cast<const float4*>(&As[k][ny * 4]);
      float av[4] = {a4.x, a4.y, a4.z, a4.w};
      #pragma unroll
      for (int j = 0; j < 4; ++j) {
        float4 b4 = *reinterpret_cast<const float4*>(&Bs[k][cx * 4 + 64 * j]);
        float bv[4] = {b4.x, b4.y, b4.z, b4.w};
        #pragma unroll
        for (int i = 0; i < 4; ++i)
          #pragma unroll
          for (int jj = 0; jj < 4; ++jj)
            acc[i][4 * j + jj] += av[i] * bv[jj];
      }
    }
    __syncthreads();
  }

  // ---- bias + relu -> hreg ----
  float hreg[4][16];
  #pragma unroll
  for (int j = 0; j < 4; ++j) {
    float4 bb = *reinterpret_cast<const float4*>(&b1[cx * 4 + 64 * j]);
    float bv[4] = {bb.x, bb.y, bb.z, bb.w};
    #pragma unroll
    for (int i = 0; i < 4; ++i)
      #pragma unroll
      for (int jj = 0; jj < 4; ++jj)
        hreg[i][4 * j + jj] = fmaxf(acc[i][4 * j + jj] + bv[jj], 0.0f);
  }

  // ---- GEMM2 via LDS chunks: thread (tx,ty): col m=tx, nodes ty*16..+15 ----
  const int tx = t & 63;
  const int ty = t >> 6;
  float acc2[16];
  #pragma unroll
  for (int i = 0; i < 16; ++i) acc2[i] = 0.0f;

  for (int c = 0; c < 4; ++c) {
    // thread's cols with j==c are exactly chunk c's local cols 4cx..4cx+3
    #pragma unroll
    for (int i = 0; i < 4; ++i) {
      float4 hv = make_float4(hreg[i][4 * c + 0], hreg[i][4 * c + 1],
                              hreg[i][4 * c + 2], hreg[i][4 * c + 3]);
      *reinterpret_cast<float4*>(&Hs[ny * 4 + i][cx * 4]) = hv;
    }
    __syncthreads();
    for (int k2 = 0; k2 < 64; k2 += 4) {
      float w[4];
      #pragma unroll
      for (int q = 0; q < 4; ++q)
        w[q] = W2[(size_t)(64 * c + k2 + q) * MDIM + tx];
      #pragma unroll
      for (int i = 0; i < 16; ++i) {
        float4 hv = *reinterpret_cast<const float4*>(&Hs[ty * 16 + i][k2]);
        acc2[i] += hv.x * w[0] + hv.y * w[1] + hv.z * w[2] + hv.w * w[3];
      }
    }
    __syncthreads();
  }

  // ---- pool atomics ----
  float bias2 = b2[tx];
  #pragma unroll
  for (int i = 0; i < 16; ++i) {
    int node = n0 + ty * 16 + i;
    if (node < N) {
      int g = batch[node];
      unsafeAtomicAdd(&sums[(size_t)g * MDIM + tx], acc2[i] + bias2);
    }
  }
}

// ---------------- out = sums / max(counts,1) ----------------
__global__ __launch_bounds__(256) void final_div_k(
    const float* __restrict__ sums, const float* __restrict__ counts,
    float* __restrict__ out) {
  int i = blockIdx.x * 256 + threadIdx.x;
  if (i >= GNUM * MDIM) return;
  int g = i >> 6;
  out[i] = sums[i] / fmaxf(counts[g], 1.0f);
}

extern "C" void kernel_launch(void* const* d_in, const int* in_sizes, int n_in,
                              void* d_out, int out_size, void* d_ws, size_t ws_size,
                              hipStream_t stream) {
  const float* x   = (const float*)d_in[0];
  const int* ei    = (const int*)d_in[1];
  const int* batch = (const int*)d_in[2];
  const float* W1  = (const float*)d_in[3];
  const float* b1  = (const float*)d_in[4];
  const float* W2  = (const float*)d_in[5];
  const float* b2  = (const float*)d_in[6];
  float* out = (float*)d_out;

  const int N = in_sizes[0] / HDIM;   // 100000
  const int E = in_sizes[1] / 2;      // 400000

  float* ws     = (float*)d_ws;
  float* neigh  = ws;                          // N*H
  float* deg    = neigh + (size_t)N * HDIM;    // N
  float* scl    = deg + N;                     // N
  float* sums   = scl + N;                     // G*M
  float* counts = sums + GNUM * MDIM;          // G
  size_t zero_floats = (size_t)N * HDIM + 2 * (size_t)N + GNUM * MDIM + GNUM;
  hipMemsetAsync(d_ws, 0, zero_floats * sizeof(float), stream);

  edge_scatter_k<<<(E + 3) / 4, 256, 0, stream>>>(x, ei, neigh, deg, E);
  finalize_k<<<(N + 255) / 256, 256, 0, stream>>>(deg, scl, batch, counts, N);
  fused_mlp_pool_k<<<(N + 63) / 64, 256, 0, stream>>>(x, neigh, scl, batch, W1, b1,
                                                      W2, b2, sums, N);
  final_div_k<<<(GNUM * MDIM + 255) / 256, 256, 0, stream>>>(sums, counts, out);
}

// Round 2
// 879.525 us; speedup vs baseline: 3.0990x; 3.0990x over previous
//
#include <hip/hip_runtime.h>

#define HDIM 256
#define MDIM 64
#define GNUM 128
#define KT 16

// ============ CSR build: count ============
__global__ __launch_bounds__(256) void count_k(const int* __restrict__ ei,
                                               int* __restrict__ degInt, int E) {
  int e = blockIdx.x * 256 + threadIdx.x;
  if (e >= E) return;
  atomicAdd(&degInt[ei[e]], 1);
}

// ============ scan level 1: per-1024-block exclusive offsets + block totals ============
__global__ __launch_bounds__(256) void scan1_k(const int* __restrict__ degInt,
                                               int* __restrict__ nodeOff,
                                               int* __restrict__ blkSum, int N) {
  __shared__ int sdata[256];
  int b = blockIdx.x, t = threadIdx.x;
  int base = b * 1024 + t * 4;
  int v[4];
  #pragma unroll
  for (int q = 0; q < 4; ++q) v[q] = (base + q < N) ? degInt[base + q] : 0;
  int tsum = v[0] + v[1] + v[2] + v[3];
  sdata[t] = tsum;
  __syncthreads();
  for (int off = 1; off < 256; off <<= 1) {
    int xv = (t >= off) ? sdata[t - off] : 0;
    __syncthreads();
    sdata[t] += xv;
    __syncthreads();
  }
  int excl = sdata[t] - tsum;   // exclusive within block
  int run = excl;
  #pragma unroll
  for (int q = 0; q < 4; ++q) {
    if (base + q < N) nodeOff[base + q] = run;
    run += v[q];
  }
  if (t == 255) blkSum[b] = sdata[255];
}

// ============ scan level 2: exclusive scan of block totals (NB <= 128) ============
__global__ __launch_bounds__(128) void scan2_k(const int* __restrict__ blkSum,
                                               int* __restrict__ blkOff, int NB) {
  __shared__ int sdata[128];
  int t = threadIdx.x;
  int v = (t < NB) ? blkSum[t] : 0;
  sdata[t] = v;
  __syncthreads();
  for (int off = 1; off < 128; off <<= 1) {
    int xv = (t >= off) ? sdata[t - off] : 0;
    __syncthreads();
    sdata[t] += xv;
    __syncthreads();
  }
  if (t < NB) blkOff[t] = sdata[t] - v;
}

// ============ scan level 3: add block offsets; init cursor ============
__global__ __launch_bounds__(256) void scan3_k(int* __restrict__ nodeOff,
                                               const int* __restrict__ blkOff,
                                               int* __restrict__ cursor, int N) {
  int i = blockIdx.x * 256 + threadIdx.x;
  if (i >= N) return;
  int off = nodeOff[i] + blkOff[i >> 10];
  nodeOff[i] = off;
  cursor[i] = off;
}

// ============ CSR fill ============
__global__ __launch_bounds__(256) void fill_k(const int* __restrict__ ei,
                                              int* __restrict__ cursor,
                                              int* __restrict__ csrDst, int E) {
  int e = blockIdx.x * 256 + threadIdx.x;
  if (e >= E) return;
  int s = ei[e];
  int d = ei[E + e];
  int p = atomicAdd(&cursor[s], 1);
  csrDst[p] = d;
}

// ============ aggregation gather: one wave per node, agg = mean of x[dst] ============
__global__ __launch_bounds__(256) void agg_k(const float* __restrict__ x,
                                             const int* __restrict__ nodeOff,
                                             const int* __restrict__ degInt,
                                             const int* __restrict__ csrDst,
                                             float* __restrict__ agg, int N) {
  int wave = blockIdx.x * 4 + (threadIdx.x >> 6);
  int lane = threadIdx.x & 63;
  if (wave >= N) return;
  int deg = degInt[wave];
  int start = nodeOff[wave];
  float4 acc = make_float4(0.f, 0.f, 0.f, 0.f);
  for (int j = 0; j < deg; ++j) {
    int d = csrDst[start + j];
    float4 v = reinterpret_cast<const float4*>(x + (size_t)d * HDIM)[lane];
    acc.x += v.x; acc.y += v.y; acc.z += v.z; acc.w += v.w;
  }
  float s = deg > 0 ? 1.0f / (float)deg : 0.0f;
  acc.x *= s; acc.y *= s; acc.z *= s; acc.w *= s;
  reinterpret_cast<float4*>(agg + (size_t)wave * HDIM)[lane] = acc;
}

// ============ fused MLP + pool ============
// Block: 256 threads, 64 nodes. Thread (cx=t&31, ny=t>>5):
//   GEMM1: nodes 8*ny+i (i 0..7), cols 4*cx + 128*j + jj (j 0..1, jj 0..3)
__global__ __launch_bounds__(256, 3) void fused_mlp_pool_k(
    const float* __restrict__ x, const float* __restrict__ agg,
    const int* __restrict__ batch,
    const float* __restrict__ W1, const float* __restrict__ b1,
    const float* __restrict__ W2, const float* __restrict__ b2,
    float* __restrict__ sums, int N) {
  __shared__ float Bs[KT][HDIM];   // 16 KB  W1 k-tile
  __shared__ float As[KT][68];     // 4.25 KB feat k-tile (pad 68)
  __shared__ float Hs[64][68];     // 17 KB  h chunk for GEMM2

  const int t  = threadIdx.x;
  const int cx = t & 31;
  const int ny = t >> 5;
  const int n0 = blockIdx.x * 64;

  float acc[8][8];
  #pragma unroll
  for (int i = 0; i < 8; ++i)
    #pragma unroll
    for (int j = 0; j < 8; ++j) acc[i][j] = 0.0f;

  for (int kt = 0; kt < 48; ++kt) {
    const int seg = kt >> 4;             // 0:x  1:agg  2:x*agg
    const int kk  = (kt & 15) * KT;
    // ---- stage A: thread t loads float4 #t: node na=t>>2, k-quad q=t&3 ----
    {
      int na = t >> 2, q = t & 3;
      int node = n0 + na;
      float4 v = make_float4(0.f, 0.f, 0.f, 0.f);
      if (node < N) {
        size_t base = (size_t)node * HDIM + kk + q * 4;
        if (seg == 0) {
          v = *reinterpret_cast<const float4*>(x + base);
        } else if (seg == 1) {
          v = *reinterpret_cast<const float4*>(agg + base);
        } else {
          float4 a = *reinterpret_cast<const float4*>(agg + base);
          float4 xx = *reinterpret_cast<const float4*>(x + base);
          v = make_float4(xx.x * a.x, xx.y * a.y, xx.z * a.z, xx.w * a.w);
        }
      }
      As[q * 4 + 0][na] = v.x;
      As[q * 4 + 1][na] = v.y;
      As[q * 4 + 2][na] = v.z;
      As[q * 4 + 3][na] = v.w;
    }
    // ---- stage B: 16 rows of W1 as float4 ----
    {
      const float4* W1v = reinterpret_cast<const float4*>(W1) + (size_t)kt * 1024;
      float4* Bsv = reinterpret_cast<float4*>(&Bs[0][0]);
      #pragma unroll
      for (int i = 0; i < 4; ++i) Bsv[t + 256 * i] = W1v[t + 256 * i];
    }
    __syncthreads();
    // ---- inner: 64 FMA / k / thread, 64 B LDS / k / thread ----
    #pragma unroll
    for (int k = 0; k < KT; ++k) {
      float4 a0 = *reinterpret_cast<const float4*>(&As[k][ny * 8]);
      float4 a1 = *reinterpret_cast<const float4*>(&As[k][ny * 8 + 4]);
      float4 b0 = *reinterpret_cast<const float4*>(&Bs[k][cx * 4]);
      float4 b1v = *reinterpret_cast<const float4*>(&Bs[k][cx * 4 + 128]);
      float av[8] = {a0.x, a0.y, a0.z, a0.w, a1.x, a1.y, a1.z, a1.w};
      float bv[8] = {b0.x, b0.y, b0.z, b0.w, b1v.x, b1v.y, b1v.z, b1v.w};
      #pragma unroll
      for (int i = 0; i < 8; ++i)
        #pragma unroll
        for (int j = 0; j < 8; ++j) acc[i][j] += av[i] * bv[j];
    }
    __syncthreads();
  }

  // ---- bias + relu in place ----
  {
    float4 bb0 = *reinterpret_cast<const float4*>(&b1[cx * 4]);
    float4 bb1 = *reinterpret_cast<const float4*>(&b1[cx * 4 + 128]);
    float bv[8] = {bb0.x, bb0.y, bb0.z, bb0.w, bb1.x, bb1.y, bb1.z, bb1.w};
    #pragma unroll
    for (int i = 0; i < 8; ++i)
      #pragma unroll
      for (int j = 0; j < 8; ++j) acc[i][j] = fmaxf(acc[i][j] + bv[j], 0.0f);
  }

  // ---- GEMM2 via 4 Hs chunks of 64 h-cols ----
  const int tx = t & 63;
  const int ty = t >> 6;
  float acc2[16];
  #pragma unroll
  for (int i = 0; i < 16; ++i) acc2[i] = 0.0f;

  for (int c = 0; c < 4; ++c) {
    // chunk c holds h cols [64c, 64c+63]: contributed by threads with cx>>4 == (c&1), j = c>>1
    if ((cx >> 4) == (c & 1)) {
      int jbase = (c >> 1) * 4;
      int cxr = cx & 15;
      #pragma unroll
      for (int i = 0; i < 8; ++i) {
        float4 hv = make_float4(acc[i][jbase + 0], acc[i][jbase + 1],
                                acc[i][jbase + 2], acc[i][jbase + 3]);
        *reinterpret_cast<float4*>(&Hs[ny * 8 + i][cxr * 4]) = hv;
      }
    }
    __syncthreads();
    for (int k2 = 0; k2 < 64; k2 += 4) {
      float w[4];
      #pragma unroll
      for (int q = 0; q < 4; ++q)
        w[q] = W2[(size_t)(64 * c + k2 + q) * MDIM + tx];
      #pragma unroll
      for (int i = 0; i < 16; ++i) {
        float4 hv = *reinterpret_cast<const float4*>(&Hs[ty * 16 + i][k2]);
        acc2[i] += hv.x * w[0] + hv.y * w[1] + hv.z * w[2] + hv.w * w[3];
      }
    }
    __syncthreads();
  }

  // ---- pool: run-length-combine per-graph, then atomic ----
  float bias2 = b2[tx];
  int i2 = 0;
  while (i2 < 16) {
    int node = n0 + ty * 16 + i2;
    if (node >= N) break;
    int g = batch[node];
    float s = acc2[i2] + bias2;
    int j2 = i2 + 1;
    while (j2 < 16) {
      int nd = n0 + ty * 16 + j2;
      if (nd >= N || batch[nd] != g) break;
      s += acc2[j2] + bias2;
      ++j2;
    }
    unsafeAtomicAdd(&sums[(size_t)g * MDIM + tx], s);
    i2 = j2;
  }
}

// ============ final: out = sums / counts (counts via binary search on sorted batch) ============
__global__ __launch_bounds__(256) void final_div_k(const float* __restrict__ sums,
                                                   const int* __restrict__ batch,
                                                   float* __restrict__ out, int N) {
  int i = blockIdx.x * 256 + threadIdx.x;
  if (i >= GNUM * MDIM) return;
  int g = i >> 6;
  int lo = 0, hi = N;
  while (lo < hi) { int mid = (lo + hi) >> 1; if (batch[mid] < g) lo = mid + 1; else hi = mid; }
  int lb = lo;
  lo = 0; hi = N;
  while (lo < hi) { int mid = (lo + hi) >> 1; if (batch[mid] < g + 1) lo = mid + 1; else hi = mid; }
  float cnt = (float)(lo - lb);
  out[i] = sums[i] / fmaxf(cnt, 1.0f);
}

extern "C" void kernel_launch(void* const* d_in, const int* in_sizes, int n_in,
                              void* d_out, int out_size, void* d_ws, size_t ws_size,
                              hipStream_t stream) {
  const float* x   = (const float*)d_in[0];
  const int* ei    = (const int*)d_in[1];
  const int* batch = (const int*)d_in[2];
  const float* W1  = (const float*)d_in[3];
  const float* b1  = (const float*)d_in[4];
  const float* W2  = (const float*)d_in[5];
  const float* b2  = (const float*)d_in[6];
  float* out = (float*)d_out;

  const int N = in_sizes[0] / HDIM;   // 100000
  const int E = in_sizes[1] / 2;      // 400000
  const int NB = (N + 1023) / 1024;   // 98

  int* degInt   = (int*)d_ws;                     // N
  float* sums   = (float*)(degInt + N);           // GNUM*MDIM
  float* agg    = sums + GNUM * MDIM;             // N*HDIM
  int* nodeOff  = (int*)(agg + (size_t)N * HDIM); // N
  int* cursor   = nodeOff + N;                    // N
  int* blkSum   = cursor + N;                     // 128
  int* blkOff   = blkSum + 128;                   // 128
  int* csrDst   = blkOff + 128;                   // E

  // zero degInt + sums (adjacent)
  hipMemsetAsync(d_ws, 0, (size_t)(N + GNUM * MDIM) * sizeof(int), stream);

  count_k<<<(E + 255) / 256, 256, 0, stream>>>(ei, degInt, E);
  scan1_k<<<NB, 256, 0, stream>>>(degInt, nodeOff, blkSum, N);
  scan2_k<<<1, 128, 0, stream>>>(blkSum, blkOff, NB);
  scan3_k<<<(N + 255) / 256, 256, 0, stream>>>(nodeOff, blkOff, cursor, N);
  fill_k<<<(E + 255) / 256, 256, 0, stream>>>(ei, cursor, csrDst, E);
  agg_k<<<(N + 3) / 4, 256, 0, stream>>>(x, nodeOff, degInt, csrDst, agg, N);
  fused_mlp_pool_k<<<(N + 63) / 64, 256, 0, stream>>>(x, agg, batch, W1, b1, W2, b2,
                                                      sums, N);
  final_div_k<<<(GNUM * MDIM + 255) / 256, 256, 0, stream>>>(sums, batch, out, N);
}

// Round 4
// 451.889 us; speedup vs baseline: 6.0316x; 1.9463x over previous
//
#include <hip/hip_runtime.h>

#define HDIM 256
#define MDIM 64
#define GNUM 128

typedef short bf16x8 __attribute__((ext_vector_type(8)));
typedef float f32x4 __attribute__((ext_vector_type(4)));
typedef unsigned short u16;
typedef unsigned int u32;

__device__ __forceinline__ u32 f2bf(float f) {
  u32 u = __float_as_uint(f);
  return (u + 0x7FFFu + ((u >> 16) & 1u)) >> 16;   // RNE
}
__device__ __forceinline__ float bf2f(u16 h) {
  return __uint_as_float((u32)h << 16);
}
__device__ __forceinline__ u32 pack2(float a, float b) {
  return f2bf(a) | (f2bf(b) << 16);
}
__device__ __forceinline__ void gload_lds16(const void* g, void* l) {
  __builtin_amdgcn_global_load_lds(
      (const __attribute__((address_space(1))) u32*)g,
      (__attribute__((address_space(3))) u32*)l, 16, 0, 0);
}

// ============ weight prep: transpose + hi/lo bf16 split ============
// W1T k-order permuted: k' = qk*192 + seg*64 + j  <->  k_global = seg*256 + qk*64 + j
__global__ __launch_bounds__(256) void prep_k(const float* __restrict__ W1,
                                              const float* __restrict__ W2,
                                              u16* __restrict__ W1Th, u16* __restrict__ W1Tl,
                                              u16* __restrict__ W2Th, u16* __restrict__ W2Tl) {
  int b = blockIdx.x, t = threadIdx.x;
  if (b < HDIM) {               // col = b
    #pragma unroll
    for (int p = 0; p < 3; ++p) {
      int kp = p * 256 + t;
      int qk = kp / 192, rem = kp - qk * 192;
      int seg = rem >> 6, j = rem & 63;
      int kg = seg * 256 + qk * 64 + j;
      float f = W1[(size_t)kg * HDIM + b];
      u16 h = (u16)f2bf(f);
      u16 lo = (u16)f2bf(f - bf2f(h));
      W1Th[b * 768 + kp] = h;
      W1Tl[b * 768 + kp] = lo;
    }
  } else {
    int m = b - HDIM;
    if (m < MDIM) {
      float f = W2[(size_t)t * MDIM + m];
      u16 h = (u16)f2bf(f);
      u16 lo = (u16)f2bf(f - bf2f(h));
      W2Th[m * 256 + t] = h;
      W2Tl[m * 256 + t] = lo;
    }
  }
}

// ============ CSR build: count ============
__global__ __launch_bounds__(256) void count_k(const int* __restrict__ ei,
                                               int* __restrict__ degInt, int E) {
  int e = blockIdx.x * 256 + threadIdx.x;
  if (e >= E) return;
  atomicAdd(&degInt[ei[e]], 1);
}

// ============ scan level 1 ============
__global__ __launch_bounds__(256) void scan1_k(const int* __restrict__ degInt,
                                               int* __restrict__ nodeOff,
                                               int* __restrict__ blkSum, int N) {
  __shared__ int sdata[256];
  int b = blockIdx.x, t = threadIdx.x;
  int base = b * 1024 + t * 4;
  int v[4];
  #pragma unroll
  for (int q = 0; q < 4; ++q) v[q] = (base + q < N) ? degInt[base + q] : 0;
  int tsum = v[0] + v[1] + v[2] + v[3];
  sdata[t] = tsum;
  __syncthreads();
  for (int off = 1; off < 256; off <<= 1) {
    int xv = (t >= off) ? sdata[t - off] : 0;
    __syncthreads();
    sdata[t] += xv;
    __syncthreads();
  }
  int run = sdata[t] - tsum;
  #pragma unroll
  for (int q = 0; q < 4; ++q) {
    if (base + q < N) nodeOff[base + q] = run;
    run += v[q];
  }
  if (t == 255) blkSum[b] = sdata[255];
}

// ============ scan level 2 ============
__global__ __launch_bounds__(128) void scan2_k(const int* __restrict__ blkSum,
                                               int* __restrict__ blkOff, int NB) {
  __shared__ int sdata[128];
  int t = threadIdx.x;
  int v = (t < NB) ? blkSum[t] : 0;
  sdata[t] = v;
  __syncthreads();
  for (int off = 1; off < 128; off <<= 1) {
    int xv = (t >= off) ? sdata[t - off] : 0;
    __syncthreads();
    sdata[t] += xv;
    __syncthreads();
  }
  if (t < NB) blkOff[t] = sdata[t] - v;
}

// ============ scan level 3 ============
__global__ __launch_bounds__(256) void scan3_k(int* __restrict__ nodeOff,
                                               const int* __restrict__ blkOff,
                                               int* __restrict__ cursor, int N) {
  int i = blockIdx.x * 256 + threadIdx.x;
  if (i >= N) return;
  int off = nodeOff[i] + blkOff[i >> 10];
  nodeOff[i] = off;
  cursor[i] = off;
}

// ============ CSR fill ============
__global__ __launch_bounds__(256) void fill_k(const int* __restrict__ ei,
                                              int* __restrict__ cursor,
                                              int* __restrict__ csrDst, int E) {
  int e = blockIdx.x * 256 + threadIdx.x;
  if (e >= E) return;
  int p = atomicAdd(&cursor[ei[e]], 1);
  csrDst[p] = ei[E + e];
}

// ============ aggregation gather: one wave per node ============
__global__ __launch_bounds__(256) void agg_k(const float* __restrict__ x,
                                             const int* __restrict__ nodeOff,
                                             const int* __restrict__ degInt,
                                             const int* __restrict__ csrDst,
                                             float* __restrict__ agg, int N) {
  int wave = blockIdx.x * 4 + (threadIdx.x >> 6);
  int lane = threadIdx.x & 63;
  if (wave >= N) return;
  int deg = degInt[wave];
  int start = nodeOff[wave];
  float4 acc = make_float4(0.f, 0.f, 0.f, 0.f);
  for (int j = 0; j < deg; ++j) {
    int d = csrDst[start + j];
    float4 v = reinterpret_cast<const float4*>(x + (size_t)d * HDIM)[lane];
    acc.x += v.x; acc.y += v.y; acc.z += v.z; acc.w += v.w;
  }
  float s = deg > 0 ? 1.0f / (float)deg : 0.0f;
  acc.x *= s; acc.y *= s; acc.z *= s; acc.w *= s;
  reinterpret_cast<float4*>(agg + (size_t)wave * HDIM)[lane] = acc;
}

// ============ fused MFMA MLP + pool (split-weight bf16) ============
// 64 nodes/block, 4 waves; wave w owns h-cols [64w, 64w+64).
// Chunk c (0..11): qk = c/3 (k-quarter of x/agg), seg = c%3 (x | agg | x*agg).
// W1T rows are pre-permuted to this k-order, so x/agg quarters load ONCE.
__global__ __launch_bounds__(256, 2) void fused_mfma_k(
    const float* __restrict__ x, const float* __restrict__ agg,
    const int* __restrict__ batch,
    const u16* __restrict__ W1Th, const u16* __restrict__ W1Tl,
    const float* __restrict__ b1,
    const u16* __restrict__ W2Th, const u16* __restrict__ W2Tl,
    const float* __restrict__ b2,
    float* __restrict__ sums, int N) {
  __shared__ __align__(16) char smem[73728];
  char* AsB = smem;                  // 8 KB  feat bf16 [64 node][64 k] swz
  char* BhB = smem + 8192;           // 32 KB W1 hi [256 hcol][64 k] swz -> later Hs[64][256]
  char* BlB = smem + 8192 + 32768;   // 32 KB W1 lo

  const int t = threadIdx.x;
  const int w = t >> 6;
  const int l = t & 63;
  const int r15 = l & 15;
  const int q = l >> 4;
  const int rx = r15 & 7;
  const int n0 = blockIdx.x * 64;

  // pre-swizzled global source for B gload_lds (linear LDS dest + inverse-swz src)
  const int colw = l >> 3;                 // row within 8-row group
  const int swz8 = ((l & 7) ^ colw) * 16;  // 16B-granule involution
  const char* w1hB = (const char*)W1Th;
  const char* w1lB = (const char*)W1Tl;

  f32x4 acc[4][4];
  #pragma unroll
  for (int i = 0; i < 4; ++i)
    #pragma unroll
    for (int j = 0; j < 4; ++j) acc[i][j] = (f32x4){0.f, 0.f, 0.f, 0.f};

  float4 pa[4], pb[4];
  #pragma unroll
  for (int p = 0; p < 4; ++p) pb[p] = make_float4(0.f, 0.f, 0.f, 0.f);

  // prologue: pa = x quarter 0
  #pragma unroll
  for (int p = 0; p < 4; ++p) {
    int g = t + 256 * p, nd = g >> 4, kq = g & 15;
    int node = n0 + nd;
    pa[p] = (node < N) ? *(const float4*)(x + (size_t)node * HDIM + kq * 4)
                       : make_float4(0.f, 0.f, 0.f, 0.f);
  }

  #pragma unroll
  for (int c = 0; c < 12; ++c) {
    const int seg = c % 3;
    __syncthreads();
    // ---- write A tile from regs (cvt bf16, swizzled 8B stores) ----
    #pragma unroll
    for (int p = 0; p < 4; ++p) {
      int g = t + 256 * p, nd = g >> 4, kq = g & 15;
      float4 v;
      if (seg == 0) v = pa[p];
      else if (seg == 1) v = pb[p];
      else v = make_float4(pa[p].x * pb[p].x, pa[p].y * pb[p].y,
                           pa[p].z * pb[p].z, pa[p].w * pb[p].w);
      int byte = (nd * 128 + kq * 8) ^ ((nd & 7) << 4);
      *(uint2*)(AsB + byte) = make_uint2(pack2(v.x, v.y), pack2(v.z, v.w));
    }
    // ---- stage W1 hi+lo: 16 x global_load_lds(16B), pre-swizzled src ----
    #pragma unroll
    for (int i = 0; i < 8; ++i) {
      size_t rowoff = (size_t)((w * 8 + i) * 8 + colw) * 1536 + c * 128 + swz8;
      gload_lds16(w1hB + rowoff, BhB + (w * 8 + i) * 1024);
      gload_lds16(w1lB + rowoff, BlB + (w * 8 + i) * 1024);
    }
    __syncthreads();
    // ---- prefetch regs for chunk c+1 (in flight during MFMA) ----
    if (c < 11) {
      const int segn = (c + 1) % 3, qkn = (c + 1) / 3;
      if (segn != 2) {
        #pragma unroll
        for (int p = 0; p < 4; ++p) {
          int g = t + 256 * p, nd = g >> 4, kq = g & 15;
          int node = n0 + nd;
          float4 v = make_float4(0.f, 0.f, 0.f, 0.f);
          if (node < N) {
            size_t off = (size_t)node * HDIM + qkn * 64 + kq * 4;
            v = (segn == 0) ? *(const float4*)(x + off) : *(const float4*)(agg + off);
          }
          if (segn == 0) pa[p] = v; else pb[p] = v;
        }
      }
    }
    // ---- MFMA: 2 k-steps x (4 ht x 4 nt) x (hi+lo) ----
    #pragma unroll
    for (int ks = 0; ks < 2; ++ks) {
      const int gb = ((ks * 4 + q) ^ rx) << 4;   // correct 3-bit granule involution
      bf16x8 bf[4];
      #pragma unroll
      for (int nt = 0; nt < 4; ++nt)
        bf[nt] = *(const bf16x8*)(AsB + (nt * 16 + r15) * 128 + gb);
      #pragma unroll
      for (int ht = 0; ht < 4; ++ht) {
        bf16x8 ah = *(const bf16x8*)(BhB + (w * 64 + ht * 16 + r15) * 128 + gb);
        bf16x8 al = *(const bf16x8*)(BlB + (w * 64 + ht * 16 + r15) * 128 + gb);
        #pragma unroll
        for (int nt = 0; nt < 4; ++nt)
          acc[ht][nt] = __builtin_amdgcn_mfma_f32_16x16x32_bf16(ah, bf[nt],
                                                                acc[ht][nt], 0, 0, 0);
        #pragma unroll
        for (int nt = 0; nt < 4; ++nt)
          acc[ht][nt] = __builtin_amdgcn_mfma_f32_16x16x32_bf16(al, bf[nt],
                                                                acc[ht][nt], 0, 0, 0);
      }
    }
  }

  // ---- h = relu(acc + b1) -> Hs bf16 (aliases BhB) ----
  __syncthreads();
  #pragma unroll
  for (int mt = 0; mt < 4; ++mt) {
    float4 b1v = *(const float4*)(b1 + w * 64 + mt * 16 + q * 4);
    #pragma unroll
    for (int nt = 0; nt < 4; ++nt) {
      f32x4 a = acc[mt][nt];
      float h0 = fmaxf(a[0] + b1v.x, 0.f);
      float h1 = fmaxf(a[1] + b1v.y, 0.f);
      float h2 = fmaxf(a[2] + b1v.z, 0.f);
      float h3 = fmaxf(a[3] + b1v.w, 0.f);
      int node = nt * 16 + r15;
      int hcol = w * 64 + mt * 16 + q * 4;
      int byte = (node * 512 + hcol * 2) ^ ((r15 & 7) << 4);
      *(uint2*)(BhB + byte) = make_uint2(pack2(h0, h1), pack2(h2, h3));
    }
  }
  __syncthreads();

  // ---- GEMM2: wave w -> nodes [16w,16w+16); emb = h @ W2 (split W2) ----
  f32x4 acc2[4];
  #pragma unroll
  for (int nt = 0; nt < 4; ++nt) acc2[nt] = (f32x4){0.f, 0.f, 0.f, 0.f};
  #pragma unroll
  for (int ks2 = 0; ks2 < 8; ++ks2) {
    int hb = ((w * 16 + r15) * 512 + ks2 * 64 + q * 16) ^ ((r15 & 7) << 4);
    bf16x8 ah = *(const bf16x8*)(BhB + hb);
    #pragma unroll
    for (int nt = 0; nt < 4; ++nt) {
      bf16x8 wbh = *(const bf16x8*)(W2Th + (nt * 16 + r15) * 256 + ks2 * 32 + q * 8);
      bf16x8 wbl = *(const bf16x8*)(W2Tl + (nt * 16 + r15) * 256 + ks2 * 32 + q * 8);
      acc2[nt] = __builtin_amdgcn_mfma_f32_16x16x32_bf16(ah, wbh, acc2[nt], 0, 0, 0);
      acc2[nt] = __builtin_amdgcn_mfma_f32_16x16x32_bf16(ah, wbl, acc2[nt], 0, 0, 0);
    }
  }

  // ---- pool: lane (r15,q) holds emb[node = 16w+4q+reg][m = nt*16+r15] ----
  float b2v[4];
  #pragma unroll
  for (int nt = 0; nt < 4; ++nt) b2v[nt] = b2[nt * 16 + r15];

  int stripbase = n0 + w * 16;
  int guni = -1;
  if (stripbase + 15 < N) {
    int gf = batch[stripbase], gl = batch[stripbase + 15];
    if (gf == gl) guni = gf;
  }
  if (guni >= 0) {
    #pragma unroll
    for (int nt = 0; nt < 4; ++nt) {
      float s = acc2[nt][0] + acc2[nt][1] + acc2[nt][2] + acc2[nt][3] + 4.0f * b2v[nt];
      s += __shfl_xor(s, 16, 64);
      s += __shfl_xor(s, 32, 64);
      if (q == 0)
        unsafeAtomicAdd(&sums[(size_t)guni * MDIM + nt * 16 + r15], s);
    }
  } else {
    int nb = stripbase + q * 4;
    int gv[4];
    #pragma unroll
    for (int r = 0; r < 4; ++r) gv[r] = (nb + r < N) ? batch[nb + r] : -1;
    #pragma unroll
    for (int nt = 0; nt < 4; ++nt) {
      float run = 0.f;
      #pragma unroll
      for (int r = 0; r < 4; ++r) {
        bool valid = gv[r] >= 0;
        run += valid ? (acc2[nt][r] + b2v[nt]) : 0.f;
        bool endrun = valid && ((r == 3) ? true : (gv[r + 1] != gv[r]));
        if (endrun) {
          unsafeAtomicAdd(&sums[(size_t)gv[r] * MDIM + nt * 16 + r15], run);
          run = 0.f;
        }
      }
    }
  }
}

// ============ final: out = sums / counts ============
__global__ __launch_bounds__(256) void final_div_k(const float* __restrict__ sums,
                                                   const int* __restrict__ batch,
                                                   float* __restrict__ out, int N) {
  int i = blockIdx.x * 256 + threadIdx.x;
  if (i >= GNUM * MDIM) return;
  int g = i >> 6;
  int lo = 0, hi = N;
  while (lo < hi) { int mid = (lo + hi) >> 1; if (batch[mid] < g) lo = mid + 1; else hi = mid; }
  int lb = lo;
  lo = 0; hi = N;
  while (lo < hi) { int mid = (lo + hi) >> 1; if (batch[mid] < g + 1) lo = mid + 1; else hi = mid; }
  float cnt = (float)(lo - lb);
  out[i] = sums[i] / fmaxf(cnt, 1.0f);
}

extern "C" void kernel_launch(void* const* d_in, const int* in_sizes, int n_in,
                              void* d_out, int out_size, void* d_ws, size_t ws_size,
                              hipStream_t stream) {
  const float* x   = (const float*)d_in[0];
  const int* ei    = (const int*)d_in[1];
  const int* batch = (const int*)d_in[2];
  const float* W1  = (const float*)d_in[3];
  const float* b1  = (const float*)d_in[4];
  const float* W2  = (const float*)d_in[5];
  const float* b2  = (const float*)d_in[6];
  float* out = (float*)d_out;

  const int N = in_sizes[0] / HDIM;   // 100000
  const int E = in_sizes[1] / 2;      // 400000
  const int NB = (N + 1023) / 1024;

  int* degInt   = (int*)d_ws;                       // N
  float* sums   = (float*)(degInt + N);             // GNUM*MDIM
  float* agg    = sums + GNUM * MDIM;               // N*HDIM
  int* nodeOff  = (int*)(agg + (size_t)N * HDIM);   // N
  int* cursor   = nodeOff + N;                      // N
  int* blkSum   = cursor + N;                       // 128
  int* blkOff   = blkSum + 128;                     // 128
  int* csrDst   = blkOff + 128;                     // E
  u16* W1Th     = (u16*)(csrDst + E);               // 256*768
  u16* W1Tl     = W1Th + 768 * HDIM;                // 256*768
  u16* W2Th     = W1Tl + 768 * HDIM;                // 64*256
  u16* W2Tl     = W2Th + 256 * MDIM;                // 64*256

  hipMemsetAsync(d_ws, 0, (size_t)(N + GNUM * MDIM) * sizeof(int), stream);

  prep_k<<<HDIM + MDIM, 256, 0, stream>>>(W1, W2, W1Th, W1Tl, W2Th, W2Tl);
  count_k<<<(E + 255) / 256, 256, 0, stream>>>(ei, degInt, E);
  scan1_k<<<NB, 256, 0, stream>>>(degInt, nodeOff, blkSum, N);
  scan2_k<<<1, 128, 0, stream>>>(blkSum, blkOff, NB);
  scan3_k<<<(N + 255) / 256, 256, 0, stream>>>(nodeOff, blkOff, cursor, N);
  fill_k<<<(E + 255) / 256, 256, 0, stream>>>(ei, cursor, csrDst, E);
  agg_k<<<(N + 3) / 4, 256, 0, stream>>>(x, nodeOff, degInt, csrDst, agg, N);
  fused_mfma_k<<<(N + 63) / 64, 256, 0, stream>>>(x, agg, batch, W1Th, W1Tl, b1,
                                                  W2Th, W2Tl, b2, sums, N);
  final_div_k<<<(GNUM * MDIM + 255) / 256, 256, 0, stream>>>(sums, batch, out, N);
}